// Round 1
// baseline (915.352 us; speedup 1.0000x reference)
//
#include <hip/hip_runtime.h>

// FilterInitializerLinear: conv3x3(512->512, pad1) on (192,512,22,22) fp32,
// PrRoIPool 4x4 per (image,seq) roi, mean over 3 images, /(C*16).
// Strategy: bf16 MFMA implicit-GEMM conv (threshold is 2% of absmax -> bf16 safe),
// padded NHWC bf16 feature tensor so the conv K-loop has zero boundary checks.

#define NIMG 192
#define CCH 512
#define FH 22
#define FW 22
#define SPATIAL 484
#define PADH 24
#define PADW 24

typedef __bf16 bf16;
typedef __bf16 bf16x8 __attribute__((ext_vector_type(8)));
typedef float f32x4 __attribute__((ext_vector_type(4)));

#define GLOBAL_AS __attribute__((address_space(1)))
#define LDS_AS __attribute__((address_space(3)))

__device__ __forceinline__ void gload_lds16(const void* g, void* l) {
  __builtin_amdgcn_global_load_lds((GLOBAL_AS const void*)g, (LDS_AS void*)l, 16, 0, 0);
}

// ---- pass 1a: feat fp32 NCHW -> bf16 padded NHWC: Fp[n][py][px][ci] ----
__global__ void cast_pad_kernel(const float* __restrict__ feat, bf16* __restrict__ Fp) {
  int bid = blockIdx.x;          // n*24 + py
  int n = bid / PADH;
  int py = bid % PADH;
  int c = threadIdx.x;           // 512 threads = ci
  int y = py - 1;
  bool yv = (y >= 0 && y < FH);
  const float* frow = feat + ((long)(n * CCH + c) * FH + (yv ? y : 0)) * FW;
  bf16* orow = Fp + ((long)(n * PADH + py) * PADW) * CCH + c;
  for (int px = 0; px < PADW; ++px) {
    int x = px - 1;
    float v = (yv && x >= 0 && x < FW) ? frow[x] : 0.f;
    orow[(long)px * CCH] = (bf16)v;
  }
}

// ---- pass 1b: conv_w (co,ci,3,3) fp32 -> Wb[co][pos][ci] bf16 ----
__global__ void wtrans_kernel(const float* __restrict__ cw, bf16* __restrict__ Wb) {
  int bid = blockIdx.x;          // co*9 + pos
  int co = bid / 9, pos = bid % 9;
  int ky = pos / 3, kx = pos % 3;
  int ci = threadIdx.x;
  Wb[(long)bid * CCH + ci] = (bf16)cw[(((long)co * CCH + ci) * 3 + ky) * 3 + kx];
}

// ---- pass 2: implicit-GEMM conv. C[co][s] = sum_{pos,ci} Wb[co][pos][ci]*Fp[n][y+ky][x+kx][ci]
// 128co x 128s tile, 4 waves (2x2), BK=64, global_load_lds w/ pre-swizzled source,
// XOR-swizzled ds_read_b128 fragments. Output O[n][co][s] bf16.
__global__ __launch_bounds__(256, 2) void conv_kernel(
    const bf16* __restrict__ Fp, const bf16* __restrict__ Wb,
    const float* __restrict__ bias, bf16* __restrict__ O) {
  __shared__ __align__(16) bf16 As[128 * 64];
  __shared__ __align__(16) bf16 Bs[128 * 64];
  int bid = blockIdx.x;
  int n = bid >> 4;
  int cot = (bid >> 2) & 3;
  int st = bid & 3;
  int co0 = cot << 7, s0 = st << 7;
  int tid = threadIdx.x;
  int wv = tid >> 6, l = tid & 63;
  int lrow = l >> 3;                 // 0..7 : row within a wave-load
  int cg = (l & 7) ^ lrow;           // pre-swizzled 16B-chunk index (global side)
  int cgoff = cg * 8;                // element offset of that chunk
  int wm = wv >> 1, wn = wv & 1;

  int arow9[4];
  long boff[4];
  #pragma unroll
  for (int j = 0; j < 4; ++j) {
    int row = j * 32 + wv * 8 + lrow;
    arow9[j] = (co0 + row) * 9;
    int sg = s0 + row;
    if (sg > SPATIAL - 1) sg = SPATIAL - 1;   // dup row; masked at store
    int sy = sg / FW, sx = sg % FW;
    boff[j] = (long)(n * PADH + sy) * PADW + sx;
  }

  const f32x4 vzero = {0.f, 0.f, 0.f, 0.f};
  f32x4 acc[4][4];
  #pragma unroll
  for (int a = 0; a < 4; ++a) {
    #pragma unroll
    for (int b = 0; b < 4; ++b) acc[a][b] = vzero;
  }

  for (int pos = 0; pos < 9; ++pos) {
    int ky = pos / 3, kx = pos % 3;
    long bshift = ((long)ky * PADW + kx) * CCH + cgoff;
    for (int ci0 = 0; ci0 < CCH; ci0 += 64) {
      #pragma unroll
      for (int j = 0; j < 4; ++j) {
        const bf16* ga = Wb + ((long)(arow9[j] + pos)) * CCH + ci0 + cgoff;
        gload_lds16(ga, (char*)As + (j * 32 + wv * 8) * 128);
        const bf16* gb = Fp + boff[j] * CCH + bshift + ci0;
        gload_lds16(gb, (char*)Bs + (j * 32 + wv * 8) * 128);
      }
      __syncthreads();
      bf16x8 af[2][4], bfr[2][4];
      #pragma unroll
      for (int kk = 0; kk < 2; ++kk) {
        #pragma unroll
        for (int mi = 0; mi < 4; ++mi) {
          int rowa = wm * 64 + mi * 16 + (l & 15);
          int offa = rowa * 128 + kk * 64 + ((l >> 4) * 16);
          offa ^= (rowa & 7) << 4;
          af[kk][mi] = *(const bf16x8*)((const char*)As + offa);
          int rowb = wn * 64 + mi * 16 + (l & 15);
          int offb = rowb * 128 + kk * 64 + ((l >> 4) * 16);
          offb ^= (rowb & 7) << 4;
          bfr[kk][mi] = *(const bf16x8*)((const char*)Bs + offb);
        }
      }
      #pragma unroll
      for (int kk = 0; kk < 2; ++kk) {
        #pragma unroll
        for (int mi = 0; mi < 4; ++mi) {
          #pragma unroll
          for (int nj = 0; nj < 4; ++nj) {
            acc[mi][nj] = __builtin_amdgcn_mfma_f32_16x16x32_bf16(
                af[kk][mi], bfr[kk][nj], acc[mi][nj], 0, 0, 0);
          }
        }
      }
      __syncthreads();
    }
  }

  // epilogue: C/D layout col=lane&15 (s), row=(lane>>4)*4+reg (co)
  #pragma unroll
  for (int mi = 0; mi < 4; ++mi) {
    #pragma unroll
    for (int nj = 0; nj < 4; ++nj) {
      #pragma unroll
      for (int r = 0; r < 4; ++r) {
        int co = co0 + wm * 64 + mi * 16 + (l >> 4) * 4 + r;
        int s = s0 + wn * 64 + nj * 16 + (l & 15);
        if (s < SPATIAL) {
          float v = acc[mi][nj][r] + bias[co];
          O[((long)n * CCH + co) * SPATIAL + s] = (bf16)v;
        }
      }
    }
  }
}

// ---- pass 3: PrRoIPool + mean over images + /(C*16). one block per sequence,
// thread = channel. Separable weights (pre-divided by bin len) in LDS. ----
__global__ void pool_kernel(const bf16* __restrict__ O, const float* __restrict__ bb,
                            float* __restrict__ out) {
  __shared__ float wys[4][FH];
  __shared__ float wxs[4][FW];
  int ns = blockIdx.x;
  int c = threadIdx.x;   // 512 threads
  float acc[4][4];
  #pragma unroll
  for (int p = 0; p < 4; ++p)
    #pragma unroll
    for (int q = 0; q < 4; ++q) acc[p][q] = 0.f;

  for (int ni = 0; ni < 3; ++ni) {
    int n = ni * 64 + ns;
    __syncthreads();   // protect LDS from previous-iteration readers
    if (threadIdx.x < 8) {
      int t = threadIdx.x;
      int axis = t >> 2;   // 0 = y, 1 = x
      int p = t & 3;
      const float scale = 1.f / 16.f;
      float bx = bb[n * 4 + 0] * scale;
      float by = bb[n * 4 + 1] * scale;
      float bw = bb[n * 4 + 2] * scale;
      float bh = bb[n * 4 + 3] * scale;
      float s0f = axis ? bx : by;
      float blen = (axis ? bw : bh) * 0.25f;
      float start = s0f + p * blen;
      float end = start + blen;
      float inv = 1.0f / blen;          // folds 1/area into the weights
      float* wrow = axis ? &wxs[p][0] : &wys[p][0];
      int size = axis ? FW : FH;
      for (int i = 0; i < size; ++i) wrow[i] = 0.f;
      int s0i = (int)floorf(start);
      for (int k = 0; k < 6; ++k) {
        int cell = s0i + k;
        float cf = (float)cell;
        float a1 = fmaxf(start, cf);
        float a2 = fmaxf(fminf(end, cf + 1.f), a1);
        float alpha = a1 - cf, lim = a2 - cf;
        float f0 = (lim - 0.5f * lim * lim) - (alpha - 0.5f * alpha * alpha);
        float f1 = 0.5f * lim * lim - 0.5f * alpha * alpha;
        if (cell >= 0 && cell < size) wrow[cell] += f0 * inv;
        if (cell + 1 >= 0 && cell + 1 < size) wrow[cell + 1] += f1 * inv;
      }
    }
    __syncthreads();
    const bf16* Op = O + ((long)n * CCH + c) * SPATIAL;
    for (int i = 0; i < FH; ++i) {
      float w0 = wys[0][i], w1 = wys[1][i], w2 = wys[2][i], w3 = wys[3][i];
      if (w0 == 0.f && w1 == 0.f && w2 == 0.f && w3 == 0.f) continue;
      for (int j = 0; j < FW; ++j) {
        float x0 = wxs[0][j], x1 = wxs[1][j], x2 = wxs[2][j], x3 = wxs[3][j];
        if (x0 == 0.f && x1 == 0.f && x2 == 0.f && x3 == 0.f) continue;
        float v = (float)Op[i * FW + j];
        float t0 = w0 * v, t1 = w1 * v, t2 = w2 * v, t3 = w3 * v;
        acc[0][0] += t0 * x0; acc[0][1] += t0 * x1; acc[0][2] += t0 * x2; acc[0][3] += t0 * x3;
        acc[1][0] += t1 * x0; acc[1][1] += t1 * x1; acc[1][2] += t1 * x2; acc[1][3] += t1 * x3;
        acc[2][0] += t2 * x0; acc[2][1] += t2 * x1; acc[2][2] += t2 * x2; acc[2][3] += t2 * x3;
        acc[3][0] += t3 * x0; acc[3][1] += t3 * x1; acc[3][2] += t3 * x2; acc[3][3] += t3 * x3;
      }
    }
  }
  const float fin = 1.f / (3.f * 512.f * 16.f);   // mean over 3 images, /(C*F*F)
  #pragma unroll
  for (int p = 0; p < 4; ++p) {
    #pragma unroll
    for (int q = 0; q < 4; ++q) {
      out[((long)(ns * CCH + c) * 4 + p) * 4 + q] = acc[p][q] * fin;
    }
  }
}

extern "C" void kernel_launch(void* const* d_in, const int* in_sizes, int n_in,
                              void* d_out, int out_size, void* d_ws, size_t ws_size,
                              hipStream_t stream) {
  const float* feat = (const float*)d_in[0];
  const float* bb = (const float*)d_in[1];
  const float* cw = (const float*)d_in[2];
  const float* cb = (const float*)d_in[3];
  float* out = (float*)d_out;

  const size_t FP_BYTES = (size_t)NIMG * PADH * PADW * CCH * 2;   // 113,246,208
  const size_t WB_BYTES = (size_t)CCH * 9 * CCH * 2;              //   4,718,592
  const size_t O_BYTES = (size_t)NIMG * CCH * SPATIAL * 2;        //  95,158,272
  if (ws_size < FP_BYTES + WB_BYTES + O_BYTES) return;  // would corrupt; fail loudly

  char* ws = (char*)d_ws;
  bf16* Fp = (bf16*)ws;
  bf16* Wb = (bf16*)(ws + FP_BYTES);
  bf16* O = (bf16*)(ws + FP_BYTES + WB_BYTES);

  hipLaunchKernelGGL(cast_pad_kernel, dim3(NIMG * PADH), dim3(CCH), 0, stream, feat, Fp);
  hipLaunchKernelGGL(wtrans_kernel, dim3(CCH * 9), dim3(CCH), 0, stream, cw, Wb);
  hipLaunchKernelGGL(conv_kernel, dim3(NIMG * 16), dim3(256), 0, stream, Fp, Wb, cb, O);
  hipLaunchKernelGGL(pool_kernel, dim3(64), dim3(CCH), 0, stream, O, bb, out);
}

// Round 2
// 695.039 us; speedup vs baseline: 1.3170x; 1.3170x over previous
//
#include <hip/hip_runtime.h>

// FilterInitializerLinear: conv3x3(512->512, pad1) on (192,512,22,22) fp32,
// PrRoIPool 4x4 per (image,seq) roi, mean over 3 images, /(C*16).
// bf16 MFMA implicit-GEMM conv; padded NHWC bf16 feature tensor.

#define NIMG 192
#define CCH 512
#define FH 22
#define FW 22
#define SPATIAL 484
#define PADH 24
#define PADW 24

typedef __bf16 bf16;
typedef __bf16 bf16x2 __attribute__((ext_vector_type(2)));
typedef __bf16 bf16x8 __attribute__((ext_vector_type(8)));
typedef float f32x4 __attribute__((ext_vector_type(4)));

#define GLOBAL_AS __attribute__((address_space(1)))
#define LDS_AS __attribute__((address_space(3)))

__device__ __forceinline__ void gload_lds16(const void* g, void* l) {
  __builtin_amdgcn_global_load_lds((GLOBAL_AS const void*)g, (LDS_AS void*)l, 16, 0, 0);
}

// ---- pass 1a: feat fp32 NCHW -> bf16 padded NHWC: Fp[n][py][px][ci] ----
__global__ void cast_pad_kernel(const float* __restrict__ feat, bf16* __restrict__ Fp) {
  int bid = blockIdx.x;          // n*24 + py
  int n = bid / PADH;
  int py = bid % PADH;
  int c = threadIdx.x;           // 512 threads = ci
  int y = py - 1;
  bool yv = (y >= 0 && y < FH);
  const float* frow = feat + ((long)(n * CCH + c) * FH + (yv ? y : 0)) * FW;
  bf16* orow = Fp + ((long)(n * PADH + py) * PADW) * CCH + c;
  for (int px = 0; px < PADW; ++px) {
    int x = px - 1;
    float v = (yv && x >= 0 && x < FW) ? frow[x] : 0.f;
    orow[(long)px * CCH] = (bf16)v;
  }
}

// ---- pass 1b: conv_w (co,ci,3,3) fp32 -> Wb[co][pos][ci] bf16 ----
__global__ void wtrans_kernel(const float* __restrict__ cw, bf16* __restrict__ Wb) {
  int bid = blockIdx.x;          // co*9 + pos
  int co = bid / 9, pos = bid % 9;
  int ky = pos / 3, kx = pos % 3;
  int ci = threadIdx.x;
  Wb[(long)bid * CCH + ci] = (bf16)cw[(((long)co * CCH + ci) * 3 + ky) * 3 + kx];
}

// ---- pass 2: implicit-GEMM conv. 128co x 128s tile, 4 waves, BK=64,
// global_load_lds w/ pre-swizzled source, XOR-swizzled ds_read_b128.
// XCD-bijective blockIdx swizzle (3072 = 8 * 384) clusters 24 images/XCD.
__global__ __launch_bounds__(256, 2) void conv_kernel(
    const bf16* __restrict__ Fp, const bf16* __restrict__ Wb,
    const float* __restrict__ bias, bf16* __restrict__ O) {
  __shared__ __align__(16) bf16 As[128 * 64];
  __shared__ __align__(16) bf16 Bs[128 * 64];
  int bid0 = blockIdx.x;
  int bid = (bid0 & 7) * 384 + (bid0 >> 3);   // XCD k gets images [24k, 24k+24)
  int n = bid >> 4;
  int cot = (bid >> 2) & 3;
  int st = bid & 3;
  int co0 = cot << 7, s0 = st << 7;
  int tid = threadIdx.x;
  int wv = tid >> 6, l = tid & 63;
  int lrow = l >> 3;                 // 0..7 : row within a wave-load
  int cg = (l & 7) ^ lrow;           // pre-swizzled 16B-chunk index (global side)
  int cgoff = cg * 8;                // element offset of that chunk
  int wm = wv >> 1, wn = wv & 1;

  int arow9[4];
  long boff[4];
  #pragma unroll
  for (int j = 0; j < 4; ++j) {
    int row = j * 32 + wv * 8 + lrow;
    arow9[j] = (co0 + row) * 9;
    int sg = s0 + row;
    if (sg > SPATIAL - 1) sg = SPATIAL - 1;   // dup row; masked at store
    int sy = sg / FW, sx = sg % FW;
    boff[j] = (long)(n * PADH + sy) * PADW + sx;
  }

  const f32x4 vzero = {0.f, 0.f, 0.f, 0.f};
  f32x4 acc[4][4];
  #pragma unroll
  for (int a = 0; a < 4; ++a) {
    #pragma unroll
    for (int b = 0; b < 4; ++b) acc[a][b] = vzero;
  }

  for (int pos = 0; pos < 9; ++pos) {
    int ky = pos / 3, kx = pos % 3;
    long bshift = ((long)ky * PADW + kx) * CCH + cgoff;
    for (int ci0 = 0; ci0 < CCH; ci0 += 64) {
      #pragma unroll
      for (int j = 0; j < 4; ++j) {
        const bf16* ga = Wb + ((long)(arow9[j] + pos)) * CCH + ci0 + cgoff;
        gload_lds16(ga, (char*)As + (j * 32 + wv * 8) * 128);
        const bf16* gb = Fp + boff[j] * CCH + bshift + ci0;
        gload_lds16(gb, (char*)Bs + (j * 32 + wv * 8) * 128);
      }
      __syncthreads();
      bf16x8 af[2][4], bfr[2][4];
      #pragma unroll
      for (int kk = 0; kk < 2; ++kk) {
        #pragma unroll
        for (int mi = 0; mi < 4; ++mi) {
          int rowa = wm * 64 + mi * 16 + (l & 15);
          int offa = rowa * 128 + kk * 64 + ((l >> 4) * 16);
          offa ^= (rowa & 7) << 4;
          af[kk][mi] = *(const bf16x8*)((const char*)As + offa);
          int rowb = wn * 64 + mi * 16 + (l & 15);
          int offb = rowb * 128 + kk * 64 + ((l >> 4) * 16);
          offb ^= (rowb & 7) << 4;
          bfr[kk][mi] = *(const bf16x8*)((const char*)Bs + offb);
        }
      }
      #pragma unroll
      for (int kk = 0; kk < 2; ++kk) {
        #pragma unroll
        for (int mi = 0; mi < 4; ++mi) {
          #pragma unroll
          for (int nj = 0; nj < 4; ++nj) {
            acc[mi][nj] = __builtin_amdgcn_mfma_f32_16x16x32_bf16(
                af[kk][mi], bfr[kk][nj], acc[mi][nj], 0, 0, 0);
          }
        }
      }
      __syncthreads();
    }
  }

  // epilogue: C/D layout col=lane&15 (s), row=(lane>>4)*4+reg (co)
  #pragma unroll
  for (int mi = 0; mi < 4; ++mi) {
    #pragma unroll
    for (int nj = 0; nj < 4; ++nj) {
      #pragma unroll
      for (int r = 0; r < 4; ++r) {
        int co = co0 + wm * 64 + mi * 16 + (l >> 4) * 4 + r;
        int s = s0 + wn * 64 + nj * 16 + (l & 15);
        if (s < SPATIAL) {
          float v = acc[mi][nj][r] + bias[co];
          O[((long)n * CCH + co) * SPATIAL + s] = (bf16)v;
        }
      }
    }
  }
}

// ---- pass 3: PrRoIPool + mean over images + /(C*16).
// grid = 64 seqs * 8 c-chunks (512 blocks, 1 wave each). Thread = channel.
// Separable weights (pre-divided by bin len -> folds 1/area) in LDS.
// Loads dword-packed (2 bf16 per uint); wave-uniform row skip on zero wy.
__global__ __launch_bounds__(64) void pool_kernel(const bf16* __restrict__ O,
                                                  const float* __restrict__ bb,
                                                  float* __restrict__ out) {
  __shared__ float wys[4][FH];
  __shared__ float wxs[4][FW];
  int ns = blockIdx.x >> 3;
  int chunk = blockIdx.x & 7;
  int lane = threadIdx.x;           // 64 threads
  int c = chunk * 64 + lane;
  f32x4 acc[4];                     // acc[p][q]
  #pragma unroll
  for (int p = 0; p < 4; ++p) acc[p] = (f32x4){0.f, 0.f, 0.f, 0.f};

  for (int ni = 0; ni < 3; ++ni) {
    int n = ni * 64 + ns;
    __syncthreads();   // protect LDS from previous-iteration readers
    if (lane < 8) {
      int t = lane;
      int axis = t >> 2;   // 0 = y, 1 = x
      int p = t & 3;
      const float scale = 1.f / 16.f;
      float bx = bb[n * 4 + 0] * scale;
      float by = bb[n * 4 + 1] * scale;
      float bw = bb[n * 4 + 2] * scale;
      float bh = bb[n * 4 + 3] * scale;
      float s0f = axis ? bx : by;
      float blen = (axis ? bw : bh) * 0.25f;
      float start = s0f + p * blen;
      float end = start + blen;
      float inv = 1.0f / blen;          // folds 1/area into the weights
      float* wrow = axis ? &wxs[p][0] : &wys[p][0];
      int size = axis ? FW : FH;
      for (int i = 0; i < size; ++i) wrow[i] = 0.f;
      int s0i = (int)floorf(start);
      for (int k = 0; k < 6; ++k) {
        int cell = s0i + k;
        float cf = (float)cell;
        float a1 = fmaxf(start, cf);
        float a2 = fmaxf(fminf(end, cf + 1.f), a1);
        float alpha = a1 - cf, lim = a2 - cf;
        float f0 = (lim - 0.5f * lim * lim) - (alpha - 0.5f * alpha * alpha);
        float f1 = 0.5f * lim * lim - 0.5f * alpha * alpha;
        if (cell >= 0 && cell < size) wrow[cell] += f0 * inv;
        if (cell + 1 >= 0 && cell + 1 < size) wrow[cell + 1] += f1 * inv;
      }
    }
    __syncthreads();
    const bf16* Op = O + ((long)n * CCH + c) * SPATIAL;
    for (int i = 0; i < FH; ++i) {
      float w0 = wys[0][i], w1 = wys[1][i], w2 = wys[2][i], w3 = wys[3][i];
      if (w0 == 0.f && w1 == 0.f && w2 == 0.f && w3 == 0.f) continue;  // wave-uniform
      const uint* rp = (const uint*)(Op + i * FW);   // element offset even -> 4B aligned
      #pragma unroll
      for (int k = 0; k < 11; ++k) {
        uint u = rp[k];
        bf16x2 pr = __builtin_bit_cast(bf16x2, u);
        #pragma unroll
        for (int h = 0; h < 2; ++h) {
          int j = 2 * k + h;
          float v = (float)pr[h];
          float x0 = wxs[0][j], x1 = wxs[1][j], x2 = wxs[2][j], x3 = wxs[3][j];
          float t0 = w0 * v, t1 = w1 * v, t2 = w2 * v, t3 = w3 * v;
          acc[0][0] += t0 * x0; acc[0][1] += t0 * x1; acc[0][2] += t0 * x2; acc[0][3] += t0 * x3;
          acc[1][0] += t1 * x0; acc[1][1] += t1 * x1; acc[1][2] += t1 * x2; acc[1][3] += t1 * x3;
          acc[2][0] += t2 * x0; acc[2][1] += t2 * x1; acc[2][2] += t2 * x2; acc[2][3] += t2 * x3;
          acc[3][0] += t3 * x0; acc[3][1] += t3 * x1; acc[3][2] += t3 * x2; acc[3][3] += t3 * x3;
        }
      }
    }
  }
  const float fin = 1.f / (3.f * 512.f * 16.f);   // mean over 3 images, /(C*F*F)
  float* outp = out + ((long)(ns * CCH + c)) * 16;   // 64B aligned
  #pragma unroll
  for (int p = 0; p < 4; ++p) {
    f32x4 v = acc[p] * fin;
    *(f32x4*)(outp + p * 4) = v;
  }
}

extern "C" void kernel_launch(void* const* d_in, const int* in_sizes, int n_in,
                              void* d_out, int out_size, void* d_ws, size_t ws_size,
                              hipStream_t stream) {
  const float* feat = (const float*)d_in[0];
  const float* bb = (const float*)d_in[1];
  const float* cw = (const float*)d_in[2];
  const float* cb = (const float*)d_in[3];
  float* out = (float*)d_out;

  const size_t FP_BYTES = (size_t)NIMG * PADH * PADW * CCH * 2;   // 113,246,208
  const size_t WB_BYTES = (size_t)CCH * 9 * CCH * 2;              //   4,718,592
  const size_t O_BYTES = (size_t)NIMG * CCH * SPATIAL * 2;        //  95,158,272
  if (ws_size < FP_BYTES + WB_BYTES + O_BYTES) return;  // would corrupt; fail loudly

  char* ws = (char*)d_ws;
  bf16* Fp = (bf16*)ws;
  bf16* Wb = (bf16*)(ws + FP_BYTES);
  bf16* O = (bf16*)(ws + FP_BYTES + WB_BYTES);

  hipLaunchKernelGGL(cast_pad_kernel, dim3(NIMG * PADH), dim3(CCH), 0, stream, feat, Fp);
  hipLaunchKernelGGL(wtrans_kernel, dim3(CCH * 9), dim3(CCH), 0, stream, cw, Wb);
  hipLaunchKernelGGL(conv_kernel, dim3(NIMG * 16), dim3(256), 0, stream, Fp, Wb, cb, O);
  hipLaunchKernelGGL(pool_kernel, dim3(64 * 8), dim3(64), 0, stream, O, bb, out);
}

// Round 3
// 528.788 us; speedup vs baseline: 1.7310x; 1.3144x over previous
//
#include <hip/hip_runtime.h>

// FilterInitializerLinear: conv3x3(512->512, pad1) on (192,512,22,22) fp32,
// PrRoIPool 4x4 per (image,seq) roi, mean over 3 images, /(C*16).
// bf16 MFMA implicit-GEMM conv with 3-deep counted-vmcnt ring pipeline.

#define NIMG 192
#define CCH 512
#define FH 22
#define FW 22
#define SPATIAL 484
#define PADH 24
#define PADW 24

typedef __bf16 bf16;
typedef __bf16 bf16x2 __attribute__((ext_vector_type(2)));
typedef __bf16 bf16x8 __attribute__((ext_vector_type(8)));
typedef float f32x4 __attribute__((ext_vector_type(4)));

#define GLOBAL_AS __attribute__((address_space(1)))
#define LDS_AS __attribute__((address_space(3)))

__device__ __forceinline__ void gload_lds16(const void* g, void* l) {
  __builtin_amdgcn_global_load_lds((GLOBAL_AS const void*)g, (LDS_AS void*)l, 16, 0, 0);
}

// ---- pass 1a: feat fp32 NCHW -> bf16 padded NHWC via LDS transpose.
// block = (n, y): reads feat[n][:][y][:] coalesced, writes padded row py=y+1
// with ci contiguous (uint-packed). Rows py=0/23 zeroed by y=0/21 blocks.
__global__ __launch_bounds__(256) void cast_pad_kernel(const float* __restrict__ feat,
                                                       bf16* __restrict__ Fp) {
  __shared__ bf16 lt[CCH * FW];   // [ci][x]
  int n = blockIdx.x / FH;
  int y = blockIdx.x % FH;
  int t = threadIdx.x;
  const float* fb = feat + (long)n * CCH * SPATIAL + y * FW;
  #pragma unroll 4
  for (int k = 0; k < 44; ++k) {            // 512*22 = 11264 = 256*44
    int f = t + 256 * k;
    int ci = f / FW;
    int x = f - ci * FW;
    lt[f] = (bf16)fb[(long)ci * SPATIAL + x];
  }
  __syncthreads();
  uint* od = (uint*)(Fp + (long)(n * PADH + y + 1) * PADW * CCH);
  #pragma unroll 4
  for (int k = 0; k < 24; ++k) {            // 24px * 256 uint = 6144 = 256*24
    int w = t + 256 * k;
    int px = w >> 8;
    int cp = w & 255;
    int ci = cp * 2;
    uint v = 0;
    if (px >= 1 && px <= FW) {
      bf16x2 pr;
      pr[0] = lt[ci * FW + px - 1];
      pr[1] = lt[(ci + 1) * FW + px - 1];
      v = __builtin_bit_cast(uint, pr);
    }
    od[w] = v;
  }
  if (y == 0 || y == FH - 1) {
    int py = (y == 0) ? 0 : PADH - 1;
    uint* oz = (uint*)(Fp + (long)(n * PADH + py) * PADW * CCH);
    #pragma unroll 4
    for (int k = 0; k < 24; ++k) oz[t + 256 * k] = 0u;
  }
}

// ---- pass 1b: conv_w (co,ci,3,3) fp32 -> Wb[co][pos][ci] bf16, via LDS ----
__global__ __launch_bounds__(512) void wtrans_kernel(const float* __restrict__ cw,
                                                     bf16* __restrict__ Wb) {
  __shared__ float lw[CCH * 9];
  int co = blockIdx.x;
  int t = threadIdx.x;
  const float* src = cw + (long)co * CCH * 9;
  #pragma unroll
  for (int k = 0; k < 9; ++k) lw[t + 512 * k] = src[t + 512 * k];
  __syncthreads();
  bf16* dst = Wb + (long)co * 9 * CCH;
  #pragma unroll
  for (int k = 0; k < 9; ++k) {
    int f = t + 512 * k;
    int pos = f >> 9;
    int ci = f & 511;
    dst[f] = (bf16)lw[ci * 9 + pos];
  }
}

// ---- pass 2: implicit-GEMM conv, 256co x 128s tile, BK=64, 8 waves (4Mx2N),
// 3-deep LDS ring, counted vmcnt(6) (loads for tile t+2 stay in flight across
// the raw s_barrier), T2 XOR swizzle, T5 setprio. 1536 blocks, XCD-swizzled.
__global__ __launch_bounds__(512, 2) void conv_kernel(
    const bf16* __restrict__ Fp, const bf16* __restrict__ Wb,
    const float* __restrict__ bias, bf16* __restrict__ O) {
  // ring buffer r: A = ring + r*24576 (256x64), B = A + 16384 (128x64)
  __shared__ __align__(16) bf16 ring[3 * 24576];   // 144 KiB
  int b0 = blockIdx.x;
  int bid = (b0 & 7) * 192 + (b0 >> 3);   // bijective XCD swizzle (1536 = 8*192)
  int n = bid >> 3;
  int mt = (bid >> 2) & 1;
  int nt = bid & 3;
  int co0 = mt << 8;
  int s0 = nt << 7;
  int tid = threadIdx.x;
  int wv = tid >> 6, l = tid & 63;
  int wm = wv >> 1, wn = wv & 1;          // 4 M-waves x 2 N-waves, 64x64 each
  int lrow = tid >> 3;                    // 0..63: staged row within 64-row block
  int cg8 = ((tid & 7) ^ (lrow & 7)) << 3;  // inverse-swizzled global chunk (elems)

  long aBase = (long)(co0 + lrow) * 9 * CCH;
  long bRow[2];
  #pragma unroll
  for (int j = 0; j < 2; ++j) {
    int sg = s0 + 64 * j + lrow;
    if (sg > SPATIAL - 1) sg = SPATIAL - 1;   // dup row; masked at store
    int sy = sg / FW, sx = sg - sy * FW;
    bRow[j] = ((long)(n * PADH + sy) * PADW + sx) * CCH + cg8;
  }

  // stage K-tile t (pos = t>>3, ci0 = (t&7)*64): 4 A-issues + 2 B-issues
  auto STAGE = [&](int t, bf16* bufA, bf16* bufB) {
    int pos = t >> 3;
    int ci0 = (t & 7) << 6;
    int ky = pos / 3;
    int kx = pos - 3 * ky;
    long ao = aBase + (long)pos * CCH + ci0 + cg8;
    #pragma unroll
    for (int j = 0; j < 4; ++j)
      gload_lds16(Wb + ao + (long)j * 64 * 9 * CCH, bufA + j * 4096 + tid * 8);
    long bsh = (long)(ky * PADW + kx) * CCH + ci0;
    #pragma unroll
    for (int j = 0; j < 2; ++j)
      gload_lds16(Fp + bRow[j] + bsh, bufB + j * 4096 + tid * 8);
  };

  // fragment read offsets (bytes), XOR bank swizzle
  int abyte[4], aswz[4], bbyte[4], bswz[4], ccol[2];
  #pragma unroll
  for (int i = 0; i < 4; ++i) {
    int ra = wm * 64 + i * 16 + (l & 15);
    abyte[i] = ra * 128; aswz[i] = (ra & 7) << 4;
    int rb = wn * 64 + i * 16 + (l & 15);
    bbyte[i] = rb * 128; bswz[i] = (rb & 7) << 4;
  }
  ccol[0] = (l >> 4) * 16;
  ccol[1] = 64 + (l >> 4) * 16;

  const f32x4 vz = {0.f, 0.f, 0.f, 0.f};
  f32x4 acc[4][4];
  #pragma unroll
  for (int a = 0; a < 4; ++a)
    #pragma unroll
    for (int b = 0; b < 4; ++b) acc[a][b] = vz;

  auto COMPUTE = [&](const bf16* bufA, const bf16* bufB) {
    bf16x8 af[2][4], bfv[2][4];
    #pragma unroll
    for (int kk = 0; kk < 2; ++kk)
      #pragma unroll
      for (int i = 0; i < 4; ++i) {
        af[kk][i] = *(const bf16x8*)((const char*)bufA + abyte[i] + (ccol[kk] ^ aswz[i]));
        bfv[kk][i] = *(const bf16x8*)((const char*)bufB + bbyte[i] + (ccol[kk] ^ bswz[i]));
      }
    __builtin_amdgcn_s_setprio(1);
    #pragma unroll
    for (int kk = 0; kk < 2; ++kk)
      #pragma unroll
      for (int mi = 0; mi < 4; ++mi)
        #pragma unroll
        for (int nj = 0; nj < 4; ++nj)
          acc[mi][nj] = __builtin_amdgcn_mfma_f32_16x16x32_bf16(
              af[kk][mi], bfv[kk][nj], acc[mi][nj], 0, 0, 0);
    __builtin_amdgcn_s_setprio(0);
  };

  bf16* A0 = ring;          bf16* B0 = A0 + 16384;
  bf16* A1 = ring + 24576;  bf16* B1 = A1 + 16384;
  bf16* A2 = ring + 49152;  bf16* B2 = A2 + 16384;

  // 72 K-tiles total (9 pos * 8 ci-steps). Invariant entering compute(t):
  // buf[t%3] ready; stage(t+1) in flight (<=6 outstanding).
  STAGE(0, A0, B0);
  STAGE(1, A1, B1);
  asm volatile("s_waitcnt vmcnt(6)" ::: "memory");   // tile 0 landed
  __builtin_amdgcn_s_barrier();

  #pragma unroll 1
  for (int tb = 0; tb < 69; tb += 3) {
    STAGE(tb + 2, A2, B2);     // buf2 last read at tb-1: barrier-protected
    COMPUTE(A0, B0);
    asm volatile("s_waitcnt vmcnt(6)" ::: "memory");  // tile tb+1 landed
    __builtin_amdgcn_s_barrier();
    STAGE(tb + 3, A0, B0);
    COMPUTE(A1, B1);
    asm volatile("s_waitcnt vmcnt(6)" ::: "memory");
    __builtin_amdgcn_s_barrier();
    STAGE(tb + 4, A1, B1);
    COMPUTE(A2, B2);
    asm volatile("s_waitcnt vmcnt(6)" ::: "memory");
    __builtin_amdgcn_s_barrier();
  }
  // t = 69
  STAGE(71, A2, B2);
  COMPUTE(A0, B0);
  asm volatile("s_waitcnt vmcnt(6)" ::: "memory");    // tile 70 landed
  __builtin_amdgcn_s_barrier();
  // t = 70
  COMPUTE(A1, B1);
  asm volatile("s_waitcnt vmcnt(0)" ::: "memory");    // tile 71 landed
  __builtin_amdgcn_s_barrier();
  // t = 71
  COMPUTE(A2, B2);

  // epilogue: C/D layout col=lane&15 (s), row=(lane>>4)*4+reg (co)
  #pragma unroll
  for (int mi = 0; mi < 4; ++mi) {
    #pragma unroll
    for (int nj = 0; nj < 4; ++nj) {
      #pragma unroll
      for (int r = 0; r < 4; ++r) {
        int co = co0 + wm * 64 + mi * 16 + (l >> 4) * 4 + r;
        int s = s0 + wn * 64 + nj * 16 + (l & 15);
        if (s < SPATIAL) {
          float v = acc[mi][nj][r] + bias[co];
          O[((long)n * CCH + co) * SPATIAL + s] = (bf16)v;
        }
      }
    }
  }
}

// ---- pass 3: PrRoIPool + mean over images + /(C*16).
// grid = 64 seqs * 8 c-chunks (512 blocks, 1 wave each).
__global__ __launch_bounds__(64) void pool_kernel(const bf16* __restrict__ O,
                                                  const float* __restrict__ bb,
                                                  float* __restrict__ out) {
  __shared__ float wys[4][FH];
  __shared__ float wxs[4][FW];
  int ns = blockIdx.x >> 3;
  int chunk = blockIdx.x & 7;
  int lane = threadIdx.x;
  int c = chunk * 64 + lane;
  f32x4 acc[4];
  #pragma unroll
  for (int p = 0; p < 4; ++p) acc[p] = (f32x4){0.f, 0.f, 0.f, 0.f};

  for (int ni = 0; ni < 3; ++ni) {
    int n = ni * 64 + ns;
    __syncthreads();
    if (lane < 8) {
      int t = lane;
      int axis = t >> 2;
      int p = t & 3;
      const float scale = 1.f / 16.f;
      float bx = bb[n * 4 + 0] * scale;
      float by = bb[n * 4 + 1] * scale;
      float bw = bb[n * 4 + 2] * scale;
      float bh = bb[n * 4 + 3] * scale;
      float s0f = axis ? bx : by;
      float blen = (axis ? bw : bh) * 0.25f;
      float start = s0f + p * blen;
      float end = start + blen;
      float inv = 1.0f / blen;
      float* wrow = axis ? &wxs[p][0] : &wys[p][0];
      int size = axis ? FW : FH;
      for (int i = 0; i < size; ++i) wrow[i] = 0.f;
      int s0i = (int)floorf(start);
      for (int k = 0; k < 6; ++k) {
        int cell = s0i + k;
        float cf = (float)cell;
        float a1 = fmaxf(start, cf);
        float a2 = fmaxf(fminf(end, cf + 1.f), a1);
        float alpha = a1 - cf, lim = a2 - cf;
        float f0 = (lim - 0.5f * lim * lim) - (alpha - 0.5f * alpha * alpha);
        float f1 = 0.5f * lim * lim - 0.5f * alpha * alpha;
        if (cell >= 0 && cell < size) wrow[cell] += f0 * inv;
        if (cell + 1 >= 0 && cell + 1 < size) wrow[cell + 1] += f1 * inv;
      }
    }
    __syncthreads();
    const bf16* Op = O + ((long)n * CCH + c) * SPATIAL;
    for (int i = 0; i < FH; ++i) {
      float w0 = wys[0][i], w1 = wys[1][i], w2 = wys[2][i], w3 = wys[3][i];
      if (w0 == 0.f && w1 == 0.f && w2 == 0.f && w3 == 0.f) continue;
      const uint* rp = (const uint*)(Op + i * FW);
      #pragma unroll
      for (int k = 0; k < 11; ++k) {
        uint u = rp[k];
        bf16x2 pr = __builtin_bit_cast(bf16x2, u);
        #pragma unroll
        for (int h = 0; h < 2; ++h) {
          int j = 2 * k + h;
          float v = (float)pr[h];
          float x0 = wxs[0][j], x1 = wxs[1][j], x2 = wxs[2][j], x3 = wxs[3][j];
          float t0 = w0 * v, t1 = w1 * v, t2 = w2 * v, t3 = w3 * v;
          acc[0][0] += t0 * x0; acc[0][1] += t0 * x1; acc[0][2] += t0 * x2; acc[0][3] += t0 * x3;
          acc[1][0] += t1 * x0; acc[1][1] += t1 * x1; acc[1][2] += t1 * x2; acc[1][3] += t1 * x3;
          acc[2][0] += t2 * x0; acc[2][1] += t2 * x1; acc[2][2] += t2 * x2; acc[2][3] += t2 * x3;
          acc[3][0] += t3 * x0; acc[3][1] += t3 * x1; acc[3][2] += t3 * x2; acc[3][3] += t3 * x3;
        }
      }
    }
  }
  const float fin = 1.f / (3.f * 512.f * 16.f);
  float* outp = out + ((long)(ns * CCH + c)) * 16;
  #pragma unroll
  for (int p = 0; p < 4; ++p) {
    f32x4 v = acc[p] * fin;
    *(f32x4*)(outp + p * 4) = v;
  }
}

extern "C" void kernel_launch(void* const* d_in, const int* in_sizes, int n_in,
                              void* d_out, int out_size, void* d_ws, size_t ws_size,
                              hipStream_t stream) {
  const float* feat = (const float*)d_in[0];
  const float* bb = (const float*)d_in[1];
  const float* cw = (const float*)d_in[2];
  const float* cb = (const float*)d_in[3];
  float* out = (float*)d_out;

  const size_t FP_BYTES = (size_t)NIMG * PADH * PADW * CCH * 2;   // 113,246,208
  const size_t WB_BYTES = (size_t)CCH * 9 * CCH * 2;              //   4,718,592
  const size_t O_BYTES = (size_t)NIMG * CCH * SPATIAL * 2;        //  95,158,272
  if (ws_size < FP_BYTES + WB_BYTES + O_BYTES) return;

  char* ws = (char*)d_ws;
  bf16* Fp = (bf16*)ws;
  bf16* Wb = (bf16*)(ws + FP_BYTES);
  bf16* O = (bf16*)(ws + FP_BYTES + WB_BYTES);

  hipLaunchKernelGGL(cast_pad_kernel, dim3(NIMG * FH), dim3(256), 0, stream, feat, Fp);
  hipLaunchKernelGGL(wtrans_kernel, dim3(CCH), dim3(512), 0, stream, cw, Wb);
  hipLaunchKernelGGL(conv_kernel, dim3(NIMG * 8), dim3(512), 0, stream, Fp, Wb, cb, O);
  hipLaunchKernelGGL(pool_kernel, dim3(64 * 8), dim3(64), 0, stream, O, bb, out);
}

// Round 4
// 297.849 us; speedup vs baseline: 3.0732x; 1.7754x over previous
//
#include <hip/hip_runtime.h>

// FilterInitializerLinear: conv3x3(512->512, pad1) on (192,512,22,22) fp32,
// PrRoIPool 4x4 per (image,seq) roi, mean over 3 images, /(C*16).
// Key insight: image n feeds exactly one roi (seq n%64) -> conv computed only
// on the compacted roi-box positions (<=256 of 484 per image, avg ~120).

#define NIMG 192
#define CCH 512
#define FH 22
#define FW 22
#define SPATIAL 484
#define PADH 24
#define PADW 24
#define OSTRIDE 256   // compacted spatial stride in O

typedef __bf16 bf16;
typedef __bf16 bf16x2 __attribute__((ext_vector_type(2)));
typedef __bf16 bf16x8 __attribute__((ext_vector_type(8)));
typedef float f32x4 __attribute__((ext_vector_type(4)));

#define GLOBAL_AS __attribute__((address_space(1)))
#define LDS_AS __attribute__((address_space(3)))

__device__ __forceinline__ void gload_lds16(const void* g, void* l) {
  __builtin_amdgcn_global_load_lds((GLOBAL_AS const void*)g, (LDS_AS void*)l, 16, 0, 0);
}

// boxes[n*8]: {y0, x0, xw, xwp, yh, countp, -, -}
// Box bounds use bin arithmetic fp-identical to pool_kernel so the box is a
// guaranteed superset of all nonzero-weight cells.
__global__ void prep_kernel(const float* __restrict__ bb, int* __restrict__ boxes) {
  int n = threadIdx.x;
  if (n >= NIMG) return;
  const float scale = 1.f / 16.f;
  float x1s = bb[n * 4 + 0] * scale;
  float y1s = bb[n * 4 + 1] * scale;
  float x2s = (bb[n * 4 + 0] + bb[n * 4 + 2]) * scale;
  float y2s = (bb[n * 4 + 1] + bb[n * 4 + 3]) * scale;
  float binx = (x2s - x1s) * 0.25f;
  float biny = (y2s - y1s) * 0.25f;
  float endx = (x1s + 3 * binx) + binx;   // exactly as pool computes bin-3 end
  float endy = (y1s + 3 * biny) + biny;
  int x0 = max(0, (int)floorf(x1s));
  int xc1 = min(FW - 1, (int)floorf(endx) + 1);
  int y0 = max(0, (int)floorf(y1s));
  int yc1 = min(FH - 1, (int)floorf(endy) + 1);
  int xw = xc1 - x0 + 1;
  int yh = yc1 - y0 + 1;
  int xwp = (xw + 1) & ~1;
  int* b = boxes + n * 8;
  b[0] = y0; b[1] = x0; b[2] = xw; b[3] = xwp; b[4] = yh; b[5] = yh * xwp;
  b[6] = 0; b[7] = 0;
}

// ---- pass 1a: feat fp32 NCHW -> bf16 padded NHWC via LDS transpose.
// Early-exits rows outside [y0-1, y1+1] (conv reads only box+halo rows).
__global__ __launch_bounds__(256) void cast_pad_kernel(const float* __restrict__ feat,
                                                       bf16* __restrict__ Fp,
                                                       const int* __restrict__ boxes) {
  __shared__ bf16 lt[CCH * FW];   // [ci][x]
  int n = blockIdx.x / FH;
  int y = blockIdx.x % FH;
  int y0 = boxes[n * 8 + 0];
  int y1 = y0 + boxes[n * 8 + 4] - 1;
  if (y < y0 - 1 || y > y1 + 1) return;
  int t = threadIdx.x;
  const float* fb = feat + (long)n * CCH * SPATIAL + y * FW;
  #pragma unroll 4
  for (int k = 0; k < 44; ++k) {            // 512*22 = 11264 = 256*44
    int f = t + 256 * k;
    int ci = f / FW;
    int x = f - ci * FW;
    lt[f] = (bf16)fb[(long)ci * SPATIAL + x];
  }
  __syncthreads();
  uint* od = (uint*)(Fp + (long)(n * PADH + y + 1) * PADW * CCH);
  #pragma unroll 4
  for (int k = 0; k < 24; ++k) {            // 24px * 256 uint = 6144 = 256*24
    int w = t + 256 * k;
    int px = w >> 8;
    int cp = w & 255;
    int ci = cp * 2;
    uint v = 0;
    if (px >= 1 && px <= FW) {
      bf16x2 pr;
      pr[0] = lt[ci * FW + px - 1];
      pr[1] = lt[(ci + 1) * FW + px - 1];
      v = __builtin_bit_cast(uint, pr);
    }
    od[w] = v;
  }
  if (y == 0 || y == FH - 1) {   // zero pad rows (only read when y0<=1 / y1==21)
    int py = (y == 0) ? 0 : PADH - 1;
    uint* oz = (uint*)(Fp + (long)(n * PADH + py) * PADW * CCH);
    #pragma unroll 4
    for (int k = 0; k < 24; ++k) oz[t + 256 * k] = 0u;
  }
}

// ---- pass 1b: conv_w (co,ci,3,3) fp32 -> Wb[co][pos][ci] bf16, via LDS ----
__global__ __launch_bounds__(512) void wtrans_kernel(const float* __restrict__ cw,
                                                     bf16* __restrict__ Wb) {
  __shared__ float lw[CCH * 9];
  int co = blockIdx.x;
  int t = threadIdx.x;
  const float* src = cw + (long)co * CCH * 9;
  #pragma unroll
  for (int k = 0; k < 9; ++k) lw[t + 512 * k] = src[t + 512 * k];
  __syncthreads();
  bf16* dst = Wb + (long)co * 9 * CCH;
  #pragma unroll
  for (int k = 0; k < 9; ++k) {
    int f = t + 512 * k;
    int pos = f >> 9;
    int ci = f & 511;
    dst[f] = (bf16)lw[ci * 9 + pos];
  }
}

// ---- pass 2: implicit-GEMM conv on compacted box positions.
// 256co x 128s tile, BK=64, 8 waves (4Mx2N), 3-deep LDS ring, counted
// vmcnt(6), T2 XOR swizzle, T5 setprio. Grid 768 = NIMG*2co*2s; s-tile 1
// early-exits when countp<=128. XCD-bijective swizzle (768 = 8*96).
__global__ __launch_bounds__(512, 2) void conv_kernel(
    const bf16* __restrict__ Fp, const bf16* __restrict__ Wb,
    const float* __restrict__ bias, bf16* __restrict__ O,
    const int* __restrict__ boxes) {
  __shared__ __align__(16) bf16 ring[3 * 24576];   // 144 KiB
  int b0 = blockIdx.x;
  int bid = (b0 & 7) * 96 + (b0 >> 3);
  int n = bid >> 2;
  int mt = (bid >> 1) & 1;
  int st = bid & 1;
  int co0 = mt << 8, s0 = st << 7;
  const int* bx = boxes + n * 8;
  int y0 = bx[0], x0 = bx[1], xw = bx[2], xwp = bx[3], countp = bx[5];
  if (s0 >= countp) return;   // block-uniform early exit

  int tid = threadIdx.x;
  int wv = tid >> 6, l = tid & 63;
  int wm = wv >> 1, wn = wv & 1;          // 4 M-waves x 2 N-waves, 64x64 each
  int lrow = tid >> 3;                    // 0..63: staged row within 64-row block
  int cg8 = ((tid & 7) ^ (lrow & 7)) << 3;  // inverse-swizzled global chunk (elems)

  long aBase = (long)(co0 + lrow) * 9 * CCH;
  long bRow[2];
  #pragma unroll
  for (int j = 0; j < 2; ++j) {
    int sg = s0 + 64 * j + lrow;
    if (sg > countp - 1) sg = countp - 1;   // dup position; store masked
    int r = sg / xwp;
    int c = sg - r * xwp;
    int sy = y0 + r, sx = x0 + c;           // sx<=21 valid (pad col reads Fp in-range)
    bRow[j] = ((long)(n * PADH + sy) * PADW + sx) * CCH + cg8;
  }

  auto STAGE = [&](int t, bf16* bufA, bf16* bufB) {
    int pos = t >> 3;
    int ci0 = (t & 7) << 6;
    int ky = pos / 3;
    int kx = pos - 3 * ky;
    long ao = aBase + (long)pos * CCH + ci0 + cg8;
    #pragma unroll
    for (int j = 0; j < 4; ++j)
      gload_lds16(Wb + ao + (long)j * 64 * 9 * CCH, bufA + j * 4096 + tid * 8);
    long bsh = (long)(ky * PADW + kx) * CCH + ci0;
    #pragma unroll
    for (int j = 0; j < 2; ++j)
      gload_lds16(Fp + bRow[j] + bsh, bufB + j * 4096 + tid * 8);
  };

  int abyte[4], aswz[4], bbyte[4], bswz[4], ccol[2];
  #pragma unroll
  for (int i = 0; i < 4; ++i) {
    int ra = wm * 64 + i * 16 + (l & 15);
    abyte[i] = ra * 128; aswz[i] = (ra & 7) << 4;
    int rb = wn * 64 + i * 16 + (l & 15);
    bbyte[i] = rb * 128; bswz[i] = (rb & 7) << 4;
  }
  ccol[0] = (l >> 4) * 16;
  ccol[1] = 64 + (l >> 4) * 16;

  const f32x4 vz = {0.f, 0.f, 0.f, 0.f};
  f32x4 acc[4][4];
  #pragma unroll
  for (int a = 0; a < 4; ++a)
    #pragma unroll
    for (int b = 0; b < 4; ++b) acc[a][b] = vz;

  auto COMPUTE = [&](const bf16* bufA, const bf16* bufB) {
    bf16x8 af[2][4], bfv[2][4];
    #pragma unroll
    for (int kk = 0; kk < 2; ++kk)
      #pragma unroll
      for (int i = 0; i < 4; ++i) {
        af[kk][i] = *(const bf16x8*)((const char*)bufA + abyte[i] + (ccol[kk] ^ aswz[i]));
        bfv[kk][i] = *(const bf16x8*)((const char*)bufB + bbyte[i] + (ccol[kk] ^ bswz[i]));
      }
    __builtin_amdgcn_s_setprio(1);
    #pragma unroll
    for (int kk = 0; kk < 2; ++kk)
      #pragma unroll
      for (int mi = 0; mi < 4; ++mi)
        #pragma unroll
        for (int nj = 0; nj < 4; ++nj)
          acc[mi][nj] = __builtin_amdgcn_mfma_f32_16x16x32_bf16(
              af[kk][mi], bfv[kk][nj], acc[mi][nj], 0, 0, 0);
    __builtin_amdgcn_s_setprio(0);
  };

  bf16* A0 = ring;          bf16* B0 = A0 + 16384;
  bf16* A1 = ring + 24576;  bf16* B1 = A1 + 16384;
  bf16* A2 = ring + 49152;  bf16* B2 = A2 + 16384;

  STAGE(0, A0, B0);
  STAGE(1, A1, B1);
  asm volatile("s_waitcnt vmcnt(6)" ::: "memory");
  __builtin_amdgcn_s_barrier();

  #pragma unroll 1
  for (int tb = 0; tb < 69; tb += 3) {
    STAGE(tb + 2, A2, B2);
    COMPUTE(A0, B0);
    asm volatile("s_waitcnt vmcnt(6)" ::: "memory");
    __builtin_amdgcn_s_barrier();
    STAGE(tb + 3, A0, B0);
    COMPUTE(A1, B1);
    asm volatile("s_waitcnt vmcnt(6)" ::: "memory");
    __builtin_amdgcn_s_barrier();
    STAGE(tb + 4, A1, B1);
    COMPUTE(A2, B2);
    asm volatile("s_waitcnt vmcnt(6)" ::: "memory");
    __builtin_amdgcn_s_barrier();
  }
  STAGE(71, A2, B2);
  COMPUTE(A0, B0);
  asm volatile("s_waitcnt vmcnt(6)" ::: "memory");
  __builtin_amdgcn_s_barrier();
  COMPUTE(A1, B1);
  asm volatile("s_waitcnt vmcnt(0)" ::: "memory");
  __builtin_amdgcn_s_barrier();
  COMPUTE(A2, B2);

  // epilogue: C/D layout col=lane&15 (s), row=(lane>>4)*4+reg (co)
  #pragma unroll
  for (int nj = 0; nj < 4; ++nj) {
    int s = s0 + wn * 64 + nj * 16 + (l & 15);
    int r = s / xwp;
    int c = s - r * xwp;
    bool ok = (s < countp) && (c < xw);
    #pragma unroll
    for (int mi = 0; mi < 4; ++mi) {
      #pragma unroll
      for (int rr = 0; rr < 4; ++rr) {
        if (ok) {
          int co = co0 + wm * 64 + mi * 16 + (l >> 4) * 4 + rr;
          float v = acc[mi][nj][rr] + bias[co];
          O[((long)n * CCH + co) * OSTRIDE + s] = (bf16)v;
        }
      }
    }
  }
}

// ---- pass 3: PrRoIPool over compacted O + mean over images + /(C*16).
// grid = 64 seqs * 8 c-chunks (512 blocks, 1 wave each).
__global__ __launch_bounds__(64) void pool_kernel(const bf16* __restrict__ O,
                                                  const float* __restrict__ bb,
                                                  const int* __restrict__ boxes,
                                                  float* __restrict__ out) {
  __shared__ float wys[4][FH];
  __shared__ float wxs[4][24];
  int ns = blockIdx.x >> 3;
  int chunk = blockIdx.x & 7;
  int lane = threadIdx.x;
  int c = chunk * 64 + lane;
  f32x4 acc[4];
  #pragma unroll
  for (int p = 0; p < 4; ++p) acc[p] = (f32x4){0.f, 0.f, 0.f, 0.f};

  for (int ni = 0; ni < 3; ++ni) {
    int n = ni * 64 + ns;
    __syncthreads();
    if (lane < 8) {
      int t = lane;
      int axis = t >> 2;
      int p = t & 3;
      const float scale = 1.f / 16.f;
      float bxv = bb[n * 4 + 0], byv = bb[n * 4 + 1];
      float bwv = bb[n * 4 + 2], bhv = bb[n * 4 + 3];
      float s1 = (axis ? bxv : byv) * scale;
      float s2 = ((axis ? bxv : byv) + (axis ? bwv : bhv)) * scale;
      float blen = (s2 - s1) * 0.25f;
      float start = s1 + p * blen;
      float end = start + blen;
      float inv = 1.0f / blen;          // folds 1/area into the weights
      float* wrow = axis ? &wxs[p][0] : &wys[p][0];
      int size = axis ? FW : FH;
      int zn = axis ? 24 : FH;
      for (int i = 0; i < zn; ++i) wrow[i] = 0.f;
      int s0i = (int)floorf(start);
      for (int k = 0; k < 6; ++k) {
        int cell = s0i + k;
        float cf = (float)cell;
        float a1 = fmaxf(start, cf);
        float a2 = fmaxf(fminf(end, cf + 1.f), a1);
        float alpha = a1 - cf, lim = a2 - cf;
        float f0 = (lim - 0.5f * lim * lim) - (alpha - 0.5f * alpha * alpha);
        float f1 = 0.5f * lim * lim - 0.5f * alpha * alpha;
        if (cell >= 0 && cell < size) wrow[cell] += f0 * inv;
        if (cell + 1 >= 0 && cell + 1 < size) wrow[cell + 1] += f1 * inv;
      }
    }
    __syncthreads();
    const int* bxp = boxes + n * 8;
    int y0 = bxp[0], x0 = bxp[1], xw = bxp[2], xwp = bxp[3], yh = bxp[4];
    const bf16* Op = O + ((long)n * CCH + c) * OSTRIDE;
    int khalf = xwp >> 1;
    for (int rr = 0; rr < yh; ++rr) {
      int y = y0 + rr;
      float w0 = wys[0][y], w1 = wys[1][y], w2 = wys[2][y], w3 = wys[3][y];
      const uint* rp = (const uint*)(Op + rr * xwp);
      for (int k = 0; k < khalf; ++k) {
        uint u = rp[k];
        bf16x2 pr = __builtin_bit_cast(bf16x2, u);
        #pragma unroll
        for (int h = 0; h < 2; ++h) {
          int j = x0 + 2 * k + h;        // absolute x; pad col has zero weight
          float v = (float)pr[h];
          float x0w = wxs[0][j], x1w = wxs[1][j], x2w = wxs[2][j], x3w = wxs[3][j];
          float t0 = w0 * v, t1 = w1 * v, t2 = w2 * v, t3 = w3 * v;
          acc[0][0] += t0 * x0w; acc[0][1] += t0 * x1w; acc[0][2] += t0 * x2w; acc[0][3] += t0 * x3w;
          acc[1][0] += t1 * x0w; acc[1][1] += t1 * x1w; acc[1][2] += t1 * x2w; acc[1][3] += t1 * x3w;
          acc[2][0] += t2 * x0w; acc[2][1] += t2 * x1w; acc[2][2] += t2 * x2w; acc[2][3] += t2 * x3w;
          acc[3][0] += t3 * x0w; acc[3][1] += t3 * x1w; acc[3][2] += t3 * x2w; acc[3][3] += t3 * x3w;
        }
      }
    }
  }
  const float fin = 1.f / (3.f * 512.f * 16.f);
  float* outp = out + ((long)(ns * CCH + c)) * 16;
  #pragma unroll
  for (int p = 0; p < 4; ++p) {
    f32x4 v = acc[p] * fin;
    *(f32x4*)(outp + p * 4) = v;
  }
}

extern "C" void kernel_launch(void* const* d_in, const int* in_sizes, int n_in,
                              void* d_out, int out_size, void* d_ws, size_t ws_size,
                              hipStream_t stream) {
  const float* feat = (const float*)d_in[0];
  const float* bb = (const float*)d_in[1];
  const float* cw = (const float*)d_in[2];
  const float* cb = (const float*)d_in[3];
  float* out = (float*)d_out;

  const size_t FP_BYTES = (size_t)NIMG * PADH * PADW * CCH * 2;     // 113,246,208
  const size_t WB_BYTES = (size_t)CCH * 9 * CCH * 2;                //   4,718,592
  const size_t O_BYTES = (size_t)NIMG * CCH * OSTRIDE * 2;          //  50,331,648
  const size_t BOX_BYTES = (size_t)NIMG * 8 * 4;                    //       6,144
  if (ws_size < FP_BYTES + WB_BYTES + O_BYTES + BOX_BYTES) return;

  char* ws = (char*)d_ws;
  bf16* Fp = (bf16*)ws;
  bf16* Wb = (bf16*)(ws + FP_BYTES);
  bf16* O = (bf16*)(ws + FP_BYTES + WB_BYTES);
  int* boxes = (int*)(ws + FP_BYTES + WB_BYTES + O_BYTES);

  hipLaunchKernelGGL(prep_kernel, dim3(1), dim3(256), 0, stream, bb, boxes);
  hipLaunchKernelGGL(cast_pad_kernel, dim3(NIMG * FH), dim3(256), 0, stream, feat, Fp, boxes);
  hipLaunchKernelGGL(wtrans_kernel, dim3(CCH), dim3(512), 0, stream, cw, Wb);
  hipLaunchKernelGGL(conv_kernel, dim3(NIMG * 4), dim3(512), 0, stream, Fp, Wb, cb, O, boxes);
  hipLaunchKernelGGL(pool_kernel, dim3(64 * 8), dim3(64), 0, stream, O, bb, boxes, out);
}